// Round 1
// 876.802 us; speedup vs baseline: 1.0009x; 1.0009x over previous
//
#include <hip/hip_runtime.h>

#define NPROP 64

typedef float vf4 __attribute__((ext_vector_type(4)));

// ---------------------------------------------------------------------------
// Phase 1: per-atom-row transform.  rows = N_ATOMS * X_DIM = 150000.
//   A[r,g] = sum_z px[r,z] * wi[z,g];  B[r,g] = sum_z px[r,z] * wj[z,g]
// Block = 64 threads (one wave): lane g owns output column g, holds
// wi[:,g] and wj[:,g] in 128 VGPRs.  Row base address depends only on
// blockIdx + uniform loop counter -> compiler scalarizes px row loads
// (s_load), so the broadcast costs no DS/VALU ops.
// UNCHANGED from previous round (tuned there; keep attribution clean).
// ---------------------------------------------------------------------------
__global__ __launch_bounds__(64, 2)
void transform_kernel(const float* __restrict__ px,
                      const float* __restrict__ wi,
                      const float* __restrict__ wj,
                      float* __restrict__ A,
                      float* __restrict__ B,
                      int nrows) {
    const int g = threadIdx.x;  // 0..63, column index

    float WA[NPROP], WB[NPROP];
#pragma unroll
    for (int z = 0; z < NPROP; ++z) {
        WA[z] = wi[z * NPROP + g];
        WB[z] = wj[z * NPROP + g];
    }

    for (int r = blockIdx.x; r < nrows; r += gridDim.x) {
        const float* __restrict__ row = px + (size_t)r * NPROP;
        float a = 0.0f, b = 0.0f;
#pragma unroll
        for (int z = 0; z < NPROP; ++z) {
            float v = row[z];  // wave-uniform -> scalar load
            a = fmaf(v, WA[z], a);
            b = fmaf(v, WB[z], b);
        }
        A[(size_t)r * NPROP + g] = a;  // coalesced 256B store
        B[(size_t)r * NPROP + g] = b;
    }
}

// ---------------------------------------------------------------------------
// Phase 2: gather + add, float4-vectorized.  48 float4 per pair (3*64 floats).
//   out4[p*48 + r] = A4[i_p*48 + r] + B4[j_p*48 + r]
// NEW this round: non-temporal output stores.  out is written once and never
// read; cacheable stores were streaming 614 MB through L2/L3 and evicting
// the 76.8 MB A/B working set, pushing the gathered reads (1.23 GB logical)
// out to HBM.  `nt` stores keep A/B L3-resident.
// ---------------------------------------------------------------------------
__global__ __launch_bounds__(256)
void gather_add_kernel(const int* __restrict__ ind,
                       const vf4* __restrict__ A,
                       const vf4* __restrict__ B,
                       vf4* __restrict__ out,
                       int total_f4) {
    int f = blockIdx.x * 256 + threadIdx.x;
    if (f >= total_f4) return;
    unsigned uf = (unsigned)f;
    unsigned pair = uf / 48u;          // magic-mul, no HW divide
    unsigned r = uf - pair * 48u;
    int i = ind[2u * pair];
    int j = ind[2u * pair + 1u];
    vf4 a = A[(size_t)i * 48u + r];    // cacheable: 16x reuse per atom, L3-resident
    vf4 b = B[(size_t)j * 48u + r];
    __builtin_nontemporal_store(a + b, out + f);  // write-once: bypass cache
}

// ---------------------------------------------------------------------------
// Fallback (only if ws_size < 76.8 MB): fused direct computation, correct
// but slow.  wi/wj staged in LDS; one wave per (pair,x) row.
// ---------------------------------------------------------------------------
__global__ __launch_bounds__(256)
void naive_fused_kernel(const int* __restrict__ ind,
                        const float* __restrict__ px,
                        const float* __restrict__ wi,
                        const float* __restrict__ wj,
                        float* __restrict__ out,
                        int npairs) {
    __shared__ float swi[NPROP * NPROP];
    __shared__ float swj[NPROP * NPROP];
    for (int t = threadIdx.x; t < NPROP * NPROP; t += 256) {
        swi[t] = wi[t];
        swj[t] = wj[t];
    }
    __syncthreads();

    const int lane = threadIdx.x & 63;
    const int w = threadIdx.x >> 6;
    const long nrows = (long)npairs * 3;
    for (long row = (long)blockIdx.x * 4 + w; row < nrows;
         row += (long)gridDim.x * 4) {
        int p = (int)(row / 3);
        int x = (int)(row - (long)p * 3);
        int i = ind[2 * p];
        int j = ind[2 * p + 1];
        const float* ri = px + ((size_t)i * 3 + x) * NPROP;
        const float* rj = px + ((size_t)j * 3 + x) * NPROP;
        float acc = 0.0f;
        for (int z = 0; z < NPROP; ++z) {
            acc = fmaf(ri[z], swi[z * NPROP + lane],
                       fmaf(rj[z], swj[z * NPROP + lane], acc));
        }
        out[row * NPROP + lane] = acc;
    }
}

extern "C" void kernel_launch(void* const* d_in, const int* in_sizes, int n_in,
                              void* d_out, int out_size, void* d_ws, size_t ws_size,
                              hipStream_t stream) {
    const int* ind = (const int*)d_in[0];     // (NPAIRS, 2) int32
    const float* px = (const float*)d_in[1];  // (NATOMS, 3, 64) fp32
    const float* wi = (const float*)d_in[2];  // (64, 64) fp32
    const float* wj = (const float*)d_in[3];  // (64, 64) fp32
    float* out = (float*)d_out;               // (NPAIRS, 3, 64) fp32

    const int npairs = in_sizes[0] / 2;
    const int nrows = in_sizes[1] / NPROP;    // NATOMS * 3

    const size_t need = 2 * (size_t)nrows * NPROP * sizeof(float);
    if (ws_size >= need) {
        float* A = (float*)d_ws;
        float* B = A + (size_t)nrows * NPROP;
        // Phase 1: 4096 blocks x 1 wave, each loops ~37 rows (weight-load
        // amortized ~37x).
        transform_kernel<<<4096, 64, 0, stream>>>(px, wi, wj, A, B, nrows);
        // Phase 2: one thread per output float4.
        int total_f4 = npairs * 48;
        gather_add_kernel<<<(total_f4 + 255) / 256, 256, 0, stream>>>(
            ind, (const vf4*)A, (const vf4*)B, (vf4*)out, total_f4);
    } else {
        naive_fused_kernel<<<8192, 256, 0, stream>>>(ind, px, wi, wj, out,
                                                     npairs);
    }
}

// Round 2
// 816.150 us; speedup vs baseline: 1.0753x; 1.0743x over previous
//
#include <hip/hip_runtime.h>

#define NPROP 64

typedef float f32x4 __attribute__((ext_vector_type(4)));
typedef short bf16x8 __attribute__((ext_vector_type(8)));   // 8 bf16 = 4 VGPRs

// fp32 -> bf16, round-to-nearest-even, pure bit ops (no dtype headers needed)
__device__ inline unsigned short f2bf(float f) {
    unsigned u = __float_as_uint(f);
    u += 0x7fffu + ((u >> 16) & 1u);
    return (unsigned short)(u >> 16);
}
__device__ inline float bf2f(unsigned short h) {
    return __uint_as_float(((unsigned)h) << 16);
}

// 8 fp32 -> hi/lo bf16 split fragments.  hi = RNE(f); lo = RNE(f - hi).
// Dropped lo*lo term ~2^-18 |v||w| per product -> absmax ~1e-4 over K=128.
__device__ inline void cvt8(float4 a, float4 b, bf16x8& hi, bf16x8& lo) {
    float f[8] = {a.x, a.y, a.z, a.w, b.x, b.y, b.z, b.w};
#pragma unroll
    for (int e = 0; e < 8; ++e) {
        unsigned short h = f2bf(f[e]);
        hi[e] = (short)h;
        lo[e] = (short)f2bf(f[e] - bf2f(h));
    }
}

// ---------------------------------------------------------------------------
// Fully fused: out[p,x,:] = px[i_p,x,:]*wi + px[j_p,x,:]*wj via MFMA.
// GEMM view: M = npairs*3 rows, N = 64, K = 128 ([vi|vj] . [wi;wj]).
// fp32 accuracy via bf16x3 split: hi.hi + lo.hi + hi.lo  (3 MFMA passes).
// Weights staged ONCE per block into LDS in pre-swizzled fragment order
// (read-only afterwards -> zero barriers in the main loop).
// Each wave owns a 16-row x 64-col output tile:
//   A frag (16x16x32_bf16): row = lane&15, k = (lane>>4)*8 + e
//   B frag:                 col = lane&15, k = (lane>>4)*8 + e
//   C/D frag (m89):         col = lane&15, row = (lane>>4)*4 + reg
// px (38.4 MB) is L2/L3-resident at 32x reuse -> gathered reads are cheap;
// the old 76.8 MB A/B round-trip (153.6 MB write + 1.23 GB HBM-ish read)
// is gone entirely.
// ---------------------------------------------------------------------------
__global__ __launch_bounds__(256)
void fused_mfma_kernel(const int* __restrict__ ind,
                       const float* __restrict__ px,
                       const float* __restrict__ wi,
                       const float* __restrict__ wj,
                       float* __restrict__ out,
                       int npairs) {
    // Fragment-order weight tiles: [sl][n][lane][e], sl,n in 0..3, 16 KB each.
    __shared__ short Bh[8192];
    __shared__ short Bl[8192];

    // ---- stage weights: [wi;wj] (128x64) -> hi/lo bf16, swizzled ----
    for (int u = threadIdx.x; u < 2048; u += 256) {   // 2048 float4 = wi+wj
        int src = u & 1023;
        const float4 v = ((const float4*)(u < 1024 ? wi : wj))[src];
        int k  = (u < 1024 ? 0 : 64) + (src >> 4);    // concat K index 0..127
        int g0 = (src & 15) * 4;                      // output column base
        int sl  = k >> 5;                             // K-slice (32 wide)
        int hi3 = (k >> 3) & 3;                       // lane>>4 group
        int e   = k & 7;                              // element within frag
        float fv[4] = {v.x, v.y, v.z, v.w};
#pragma unroll
        for (int c = 0; c < 4; ++c) {
            int g = g0 + c;
            int lane = hi3 * 16 + (g & 15);
            int n = g >> 4;
            int idx = (((sl * 4 + n) * 64 + lane) << 3) + e;
            unsigned short h = f2bf(fv[c]);
            Bh[idx] = (short)h;
            Bl[idx] = (short)f2bf(fv[c] - bf2f(h));
        }
    }
    __syncthreads();   // the only barrier; LDS is read-only below

    const int l  = threadIdx.x & 63;
    const int wv = threadIdx.x >> 6;
    const long nrows  = (long)npairs * 3;
    const int  ntiles = (int)((nrows + 15) >> 4);
    const int  nwaves = gridDim.x * 4;

    for (int t = blockIdx.x * 4 + wv; t < ntiles; t += nwaves) {
        // ---- gather this lane's A-row data (row = tile*16 + lane&15) ----
        long row = (long)t * 16 + (l & 15);
        if (row >= nrows) row = nrows - 1;            // tail clamp (loads only)
        unsigned ur = (unsigned)row;
        unsigned p  = ur / 3u;                        // magic-mul div
        unsigned x  = ur - p * 3u;
        int i = ind[2u * p];
        int j = ind[2u * p + 1u];
        const float* pi = px + ((size_t)i * 3 + x) * NPROP;
        const float* pj = px + ((size_t)j * 3 + x) * NPROP;
        int c0 = (l >> 4) * 8;                        // this lane's k-chunk
        float4 v0 = *(const float4*)(pi + c0);
        float4 v1 = *(const float4*)(pi + c0 + 4);
        float4 v2 = *(const float4*)(pi + 32 + c0);
        float4 v3 = *(const float4*)(pi + 32 + c0 + 4);
        float4 u0 = *(const float4*)(pj + c0);
        float4 u1 = *(const float4*)(pj + c0 + 4);
        float4 u2 = *(const float4*)(pj + 32 + c0);
        float4 u3 = *(const float4*)(pj + 32 + c0 + 4);

        bf16x8 Ah[4], Al[4];                          // K-slices 0..3
        cvt8(v0, v1, Ah[0], Al[0]);                   // vi k 0..31
        cvt8(v2, v3, Ah[1], Al[1]);                   // vi k 32..63
        cvt8(u0, u1, Ah[2], Al[2]);                   // vj k 0..31  (K 64..95)
        cvt8(u2, u3, Ah[3], Al[3]);                   // vj k 32..63 (K 96..127)

        // ---- 4 N-tiles x 4 K-slices x 3 passes = 48 MFMA ----
#pragma unroll
        for (int n = 0; n < 4; ++n) {
            f32x4 acc = {0.f, 0.f, 0.f, 0.f};
#pragma unroll
            for (int sl = 0; sl < 4; ++sl) {
                int bidx = ((sl * 4 + n) * 64 + l) << 3;
                bf16x8 bh = *(const bf16x8*)&Bh[bidx];
                bf16x8 bl = *(const bf16x8*)&Bl[bidx];
                acc = __builtin_amdgcn_mfma_f32_16x16x32_bf16(Ah[sl], bh, acc, 0, 0, 0);
                acc = __builtin_amdgcn_mfma_f32_16x16x32_bf16(Al[sl], bh, acc, 0, 0, 0);
                acc = __builtin_amdgcn_mfma_f32_16x16x32_bf16(Ah[sl], bl, acc, 0, 0, 0);
            }
            // ---- store: col = n*16 + (l&15), row = t*16 + (l>>4)*4 + q ----
#pragma unroll
            for (int q = 0; q < 4; ++q) {
                long grow = (long)t * 16 + (l >> 4) * 4 + q;
                if (grow < nrows)
                    __builtin_nontemporal_store(
                        acc[q], out + grow * NPROP + n * 16 + (l & 15));
            }
        }
    }
}

extern "C" void kernel_launch(void* const* d_in, const int* in_sizes, int n_in,
                              void* d_out, int out_size, void* d_ws, size_t ws_size,
                              hipStream_t stream) {
    const int* ind = (const int*)d_in[0];     // (NPAIRS, 2) int32
    const float* px = (const float*)d_in[1];  // (NATOMS, 3, 64) fp32
    const float* wi = (const float*)d_in[2];  // (64, 64) fp32
    const float* wj = (const float*)d_in[3];  // (64, 64) fp32
    float* out = (float*)d_out;               // (NPAIRS, 3, 64) fp32

    const int npairs = in_sizes[0] / 2;

    // 2048 blocks x 4 waves = 8192 waves, ~18 row-tiles each.
    // LDS 32 KB/block -> 5 blocks/CU by LDS; VGPR ~120 -> ~4 waves/SIMD.
    fused_mfma_kernel<<<2048, 256, 0, stream>>>(ind, px, wi, wj, out, npairs);
}